// Round 1
// baseline (253.030 us; speedup 1.0000x reference)
//
#include <hip/hip_runtime.h>
#include <hip/hip_bf16.h>

// NCC loss: five 9x9x9 box sums over (2,1,160,160,160) fp32 volumes, fused.
// Strategy: fully-fused separable box filter. Each block owns a 16x16 (h,w)
// tile and streams a 32-deep D-chunk with a 9-slot rolling ring buffer in LDS.
// No large workspace needed; d_ws holds only an 8-byte double accumulator.

#define NB   2
#define NDIM 160
#define TILE 16
#define RE   24      // TILE + 8 halo
#define DCHUNK 32
#define NDCHUNK (NDIM / DCHUNK)   // 5

__global__ __launch_bounds__(256)
void ncc_main(const float* __restrict__ I, const float* __restrict__ J,
              double* __restrict__ out_acc) {
    const int t  = threadIdx.x;
    const int tx = t & 15;
    const int ty = t >> 4;
    const int w0 = blockIdx.x * TILE;
    const int h0 = blockIdx.y * TILE;
    const int b  = blockIdx.z / NDCHUNK;
    const int d0 = (blockIdx.z % NDCHUNK) * DCHUNK;

    const float* Ib = I + (size_t)b * NDIM * NDIM * NDIM;
    const float* Jb = J + (size_t)b * NDIM * NDIM * NDIM;

    __shared__ float sI[RE][25];          // 25 = 24+1 pad
    __shared__ float sJ[RE][25];
    __shared__ float rs[5][RE][TILE];     // row sums (along W) per channel
    __shared__ float ring[9][5][256];     // per-thread ring: thread-private slots
    __shared__ double wsum[4];

    // Zero ring. Thread t zeroes exactly the indices with (i % 256) == t,
    // which are precisely its own private slots -> no barrier needed.
    for (int i = t; i < 9 * 5 * 256; i += 256) ((float*)ring)[i] = 0.0f;

    float acc[5] = {0.f, 0.f, 0.f, 0.f, 0.f};
    double csum = 0.0;

    // Compute HW box sums for slice dz (0 <= dz < NDIM), result in s[5].
    auto compute_slice = [&](int dz, float s[5]) {
        __syncthreads();  // previous iteration's readers of sI/sJ/rs are done
        // Step A: stage 24x24 halo region (zero padded) for I and J
        for (int e = t; e < RE * RE; e += 256) {
            int r = e / RE, c = e % RE;
            int h = h0 - 4 + r, w = w0 - 4 + c;
            float vi = 0.f, vj = 0.f;
            if (h >= 0 && h < NDIM && w >= 0 && w < NDIM) {
                size_t idx = ((size_t)dz * NDIM + h) * NDIM + w;
                vi = Ib[idx];
                vj = Jb[idx];
            }
            sI[r][c] = vi;
            sJ[r][c] = vj;
        }
        __syncthreads();
        // Step B: 9-tap row sums along W for 5 channels. 24 rows x 16 cols.
        for (int p = t; p < RE * TILE; p += 256) {
            int r = p >> 4, wo = p & 15;
            float a0 = 0.f, a1 = 0.f, a2 = 0.f, a3 = 0.f, a4 = 0.f;
#pragma unroll
            for (int k = 0; k < 9; ++k) {
                float vi = sI[r][wo + k];
                float vj = sJ[r][wo + k];
                a0 += vi; a1 += vj;
                a2 += vi * vi; a3 += vj * vj; a4 += vi * vj;
            }
            rs[0][r][wo] = a0; rs[1][r][wo] = a1; rs[2][r][wo] = a2;
            rs[3][r][wo] = a3; rs[4][r][wo] = a4;
        }
        __syncthreads();
        // Step C: 9-tap column sums along H; each thread owns (ty, tx).
#pragma unroll
        for (int c = 0; c < 5; ++c) {
            float sum = 0.f;
#pragma unroll
            for (int k = 0; k < 9; ++k) sum += rs[c][ty + k][tx];
            s[c] = sum;
        }
    };

    // Prologue: slices d0-4 .. d0+3 (clipped at 0; d0+3 <= 131 < 160 always).
    for (int dz = d0 - 4; dz <= d0 + 3; ++dz) {
        if (dz < 0) continue;  // block-uniform
        float s[5];
        compute_slice(dz, s);
        int slot = dz % 9;
#pragma unroll
        for (int c = 0; c < 5; ++c) {
            ring[slot][c][t] = s[c];
            acc[c] += s[c];
        }
    }

    const float inv_win = 1.0f / 729.0f;

    // Main loop: 32 outputs along D.
    for (int dd = 0; dd < DCHUNK; ++dd) {
        int d = d0 + dd;
        int dz = d + 4;
        float s[5] = {0.f, 0.f, 0.f, 0.f, 0.f};
        if (dz < NDIM) compute_slice(dz, s);  // block-uniform condition
        int slot = dz % 9;
#pragma unroll
        for (int c = 0; c < 5; ++c) {
            float old = ring[slot][c][t];   // slice d-5 (or 0 if nonexistent)
            ring[slot][c][t] = s[c];
            acc[c] += s[c] - old;
        }
        float Is = acc[0], Js = acc[1], I2 = acc[2], J2 = acc[3], IJ = acc[4];
        float cross = IJ - Is * Js * inv_win;
        float Ivar  = I2 - Is * Is * inv_win;
        float Jvar  = J2 - Js * Js * inv_win;
        float cc = cross * cross / (Ivar * Jvar + 1e-5f);
        csum += (double)cc;
    }

    // Block reduction: wave shuffle then cross-wave via LDS.
#pragma unroll
    for (int off = 32; off > 0; off >>= 1)
        csum += __shfl_down(csum, off, 64);
    if ((t & 63) == 0) wsum[t >> 6] = csum;
    __syncthreads();
    if (t == 0) {
        double total = wsum[0] + wsum[1] + wsum[2] + wsum[3];
        atomicAdd(out_acc, total);
    }
}

__global__ void ncc_finalize(const double* __restrict__ acc,
                             float* __restrict__ out) {
    out[0] = (float)(-acc[0] / 8192000.0);
}

extern "C" void kernel_launch(void* const* d_in, const int* in_sizes, int n_in,
                              void* d_out, int out_size, void* d_ws, size_t ws_size,
                              hipStream_t stream) {
    const float* I = (const float*)d_in[0];   // y_true
    const float* J = (const float*)d_in[1];   // y_pred
    double* acc = (double*)d_ws;

    hipMemsetAsync(acc, 0, sizeof(double), stream);

    dim3 grid(NDIM / TILE, NDIM / TILE, NB * NDCHUNK);  // 10 x 10 x 10
    ncc_main<<<grid, 256, 0, stream>>>(I, J, acc);
    ncc_finalize<<<1, 1, 0, stream>>>(acc, (float*)d_out);
}

// Round 2
// 173.783 us; speedup vs baseline: 1.4560x; 1.4560x over previous
//
#include <hip/hip_runtime.h>
#include <hip/hip_bf16.h>

// NCC loss: five 9x9x9 box sums over (2,1,160,160,160) fp32 volumes, fused.
// Separable box filter; block owns a 16x16 (h,w) tile, streams 32 outputs
// along D. D-direction 9-tap window kept in REGISTERS (ring[9][5], slot index
// made compile-time by outer-5 x inner-unrolled-9 loop structure).
// LDS: double-buffered staging + row sums, 2 barriers per slice.
// d_ws holds one double accumulator.

#define NB   2
#define NDIM 160
#define TILE 16
#define RE   24      // TILE + 8 halo
#define DCHUNK 32
#define NDCHUNK (NDIM / DCHUNK)   // 5

__global__ __launch_bounds__(256, 4)
void ncc_main(const float* __restrict__ I, const float* __restrict__ J,
              double* __restrict__ out_acc) {
    const int t  = threadIdx.x;
    const int tx = t & 15;
    const int ty = t >> 4;
    const int w0 = blockIdx.x * TILE;
    const int h0 = blockIdx.y * TILE;
    const int b  = blockIdx.z / NDCHUNK;
    const int d0 = (blockIdx.z % NDCHUNK) * DCHUNK;

    const float* Ib = I + (size_t)b * NDIM * NDIM * NDIM;
    const float* Jb = J + (size_t)b * NDIM * NDIM * NDIM;

    // Double-buffered LDS (2 barriers/slice instead of 3):
    __shared__ float2 sIJ[2][RE][25];       // interleaved I,J halo (col pad)
    __shared__ float4 rsv[2][RE][TILE];     // row sums: {I, J, I2, J2}
    __shared__ float  rss[2][RE][TILE];     // row sums: IJ
    __shared__ double wsum[4];

    // D-window ring in REGISTERS: ring[j][c], j indexed by constants only.
    float ring[9][5];
#pragma unroll
    for (int k = 0; k < 9; ++k)
#pragma unroll
        for (int c = 0; c < 5; ++c) ring[k][c] = 0.0f;

    float acc[5] = {0.f, 0.f, 0.f, 0.f, 0.f};
    double csum = 0.0;
    int pb = 0;
    const float inv_win = 1.0f / 729.0f;

    // 45 steps (40 real + 5 dummy so step%9 == j is exact); slice dz = d0-4+step.
    // After folding slice dz, acc = box-sum over slices [dz-8, dz]; output
    // d = dz-4 is emitted for steps 8..39.
    for (int o = 0; o < 5; ++o) {
#pragma unroll
        for (int j = 0; j < 9; ++j) {
            const int step = o * 9 + j;
            const int dz = d0 - 4 + step;
            float s[5] = {0.f, 0.f, 0.f, 0.f, 0.f};
            if (step < 40 && dz >= 0 && dz < NDIM) {   // block-uniform
                // Phase A: stage 24x24 halo (zero-padded) as float2
                for (int e = t; e < RE * RE; e += 256) {
                    int r = e / RE, c2 = e - r * RE;
                    int h = h0 - 4 + r, w = w0 - 4 + c2;
                    float vi = 0.f, vj = 0.f;
                    if ((unsigned)h < NDIM && (unsigned)w < NDIM) {
                        size_t idx = ((size_t)dz * NDIM + h) * NDIM + w;
                        vi = Ib[idx];
                        vj = Jb[idx];
                    }
                    sIJ[pb][r][c2] = make_float2(vi, vj);
                }
                __syncthreads();
                // Phase B: 9-tap row sums along W, 5 channels, 24x16 items
                for (int p = t; p < RE * TILE; p += 256) {
                    int r = p >> 4, wo = p & 15;
                    float a0 = 0.f, a1 = 0.f, a2 = 0.f, a3 = 0.f, a4 = 0.f;
#pragma unroll
                    for (int k = 0; k < 9; ++k) {
                        float2 v = sIJ[pb][r][wo + k];
                        a0 += v.x; a1 += v.y;
                        a2 += v.x * v.x; a3 += v.y * v.y; a4 += v.x * v.y;
                    }
                    rsv[pb][r][wo] = make_float4(a0, a1, a2, a3);
                    rss[pb][r][wo] = a4;
                }
                __syncthreads();
                // Phase C: 9-tap column sums along H at (ty, tx)
                float s0 = 0.f, s1 = 0.f, s2 = 0.f, s3 = 0.f, s4 = 0.f;
#pragma unroll
                for (int k = 0; k < 9; ++k) {
                    float4 v = rsv[pb][ty + k][tx];
                    s0 += v.x; s1 += v.y; s2 += v.z; s3 += v.w;
                    s4 += rss[pb][ty + k][tx];
                }
                s[0] = s0; s[1] = s1; s[2] = s2; s[3] = s3; s[4] = s4;
                pb ^= 1;
            }
            // Slide the D-window (constant slot j -> pure registers)
#pragma unroll
            for (int c = 0; c < 5; ++c) {
                acc[c] += s[c] - ring[j][c];
                ring[j][c] = s[c];
            }
            if (step >= 8 && step < 40) {
                float Is = acc[0], Js = acc[1];
                float I2 = acc[2], J2 = acc[3], IJ = acc[4];
                float cross = IJ - Is * Js * inv_win;
                float Ivar  = I2 - Is * Is * inv_win;
                float Jvar  = J2 - Js * Js * inv_win;
                float cc = cross * cross / (Ivar * Jvar + 1e-5f);
                csum += (double)cc;
            }
        }
    }

    // Block reduction: wave shuffle, then cross-wave via LDS.
#pragma unroll
    for (int off = 32; off > 0; off >>= 1)
        csum += __shfl_down(csum, off, 64);
    if ((t & 63) == 0) wsum[t >> 6] = csum;
    __syncthreads();
    if (t == 0) {
        double total = wsum[0] + wsum[1] + wsum[2] + wsum[3];
        atomicAdd(out_acc, total);
    }
}

__global__ void ncc_finalize(const double* __restrict__ acc,
                             float* __restrict__ out) {
    out[0] = (float)(-acc[0] / 8192000.0);
}

extern "C" void kernel_launch(void* const* d_in, const int* in_sizes, int n_in,
                              void* d_out, int out_size, void* d_ws, size_t ws_size,
                              hipStream_t stream) {
    const float* I = (const float*)d_in[0];   // y_true
    const float* J = (const float*)d_in[1];   // y_pred
    double* acc = (double*)d_ws;

    hipMemsetAsync(acc, 0, sizeof(double), stream);

    dim3 grid(NDIM / TILE, NDIM / TILE, NB * NDCHUNK);  // 10 x 10 x 10
    ncc_main<<<grid, 256, 0, stream>>>(I, J, acc);
    ncc_finalize<<<1, 1, 0, stream>>>(acc, (float*)d_out);
}